// Round 1
// baseline (136.120 us; speedup 1.0000x reference)
//
#include <hip/hip_runtime.h>
#include <math.h>

#define BATCH 8
#define BN    512          // rois per frame
#define NC    37           // classes incl. background
#define NFG   36           // foreground classes
#define FD    2048         // feature dim

// Output layout (flat float32 in d_out, reference return order):
//   cls_dets  [B, NFG, BN, 5]  -> 737280 floats at offset 0
//   kept_feats[B, BN, FD]      -> 8388608 floats at offset 737280
//   keep      [B, NFG, BN]     -> 147456 floats (0/1) at offset 9125888

// -------------------- Kernel 1: decode + sort + greedy NMS ------------------
// One block per (batch, fg-class). 256 threads handle 512 boxes (2 each).
__global__ __launch_bounds__(256) void nms_kernel(
    const float* __restrict__ rois,       // [B,BN,5] (bidx,x1,y1,x2,y2)
    const float* __restrict__ bbox_pred,  // [B,BN,4*NC]
    const float* __restrict__ scores,     // [B,BN,NC]
    const float* __restrict__ im_info,    // [B,3] (h,w,scale)
    float* __restrict__ cls_dets,         // [B,NFG,BN,5]
    float* __restrict__ keep_out)         // [B,NFG,BN]
{
    const int bc  = blockIdx.x;
    const int b   = bc / NFG;
    const int cc  = bc % NFG;   // 0..35
    const int c   = cc + 1;     // original class index 1..36
    const int tid = threadIdx.x;

    __shared__ float sb[BN][4];      // decoded clipped boxes, by ORIGINAL index
    __shared__ float sarea[BN];      // areas, by original index
    __shared__ float skey[BN];       // sort key: score if valid else -inf (sorted order)
    __shared__ int   sidx[BN];       // original index (sorted order)
    __shared__ unsigned char srem[BN]; // remaining (not suppressed), sorted order
    __shared__ int   sV;             // number of valid boxes

    if (tid == 0) sV = 0;
    __syncthreads();

    const float xmax = im_info[b * 3 + 1] - 1.0f;
    const float ymax = im_info[b * 3 + 0] - 1.0f;

    int vcnt = 0;
    for (int n = tid; n < BN; n += 256) {
        const float* r = rois + (size_t)(b * BN + n) * 5;
        const float x1r = r[1], y1r = r[2], x2r = r[3], y2r = r[4];
        const float w  = x2r - x1r;
        const float h  = y2r - y1r;
        const float cx = x1r + 0.5f * w;
        const float cy = y1r + 0.5f * h;
        const float* dp = bbox_pred + (size_t)(b * BN + n) * (4 * NC) + 4 * c;
        const float dx  = dp[0] * 0.1f;
        const float dy  = dp[1] * 0.1f;
        const float dlw = dp[2] * 0.2f;
        const float dlh = dp[3] * 0.2f;
        const float px = dx * w + cx;
        const float py = dy * h + cy;
        const float pw = expf(dlw) * w;
        const float ph = expf(dlh) * h;
        float bx1 = px - 0.5f * pw;
        float by1 = py - 0.5f * ph;
        float bx2 = px + 0.5f * pw;
        float by2 = py + 0.5f * ph;
        bx1 = fminf(fmaxf(bx1, 0.0f), xmax);
        by1 = fminf(fmaxf(by1, 0.0f), ymax);
        bx2 = fminf(fmaxf(bx2, 0.0f), xmax);
        by2 = fminf(fmaxf(by2, 0.0f), ymax);
        sb[n][0] = bx1; sb[n][1] = by1; sb[n][2] = bx2; sb[n][3] = by2;
        sarea[n] = (bx2 - bx1) * (by2 - by1);
        const float s = scores[(size_t)(b * BN + n) * NC + c];
        const bool valid = s > 0.1f;
        skey[n] = valid ? s : -INFINITY;
        sidx[n] = n;
        if (valid) vcnt++;
    }
    atomicAdd(&sV, vcnt);

    // Bitonic sort of (skey, sidx): descending score, ascending index on ties
    // (matches jnp's stable argsort of -score with invalid -> -inf).
    for (unsigned k = 2; k <= BN; k <<= 1) {
        for (unsigned j = k >> 1; j > 0; j >>= 1) {
            __syncthreads();
            for (unsigned i = tid; i < BN; i += 256) {
                const unsigned ixj = i ^ j;
                if (ixj > i) {
                    const float ka = skey[i], kb = skey[ixj];
                    const int   ia = sidx[i], ib = sidx[ixj];
                    // strict total order: a before b?
                    const bool a_first = (ka > kb) || (ka == kb && ia < ib);
                    const bool up = ((i & k) == 0);
                    const bool do_swap = up ? !a_first : a_first;
                    if (do_swap) {
                        skey[i] = kb; skey[ixj] = ka;
                        sidx[i] = ib; sidx[ixj] = ia;
                    }
                }
            }
        }
    }
    __syncthreads();

    const int V = sV;  // valid boxes occupy sorted prefix [0, V)
    for (int i = tid; i < BN; i += 256) srem[i] = (i < V) ? 1 : 0;

    // Greedy NMS: process sorted order; kept box suppresses later overlaps.
    for (int i = 0; i < V; ++i) {
        __syncthreads();
        if (!srem[i]) continue;            // uniform branch (shared read)
        const int   ni  = sidx[i];
        const float ax1 = sb[ni][0], ay1 = sb[ni][1];
        const float ax2 = sb[ni][2], ay2 = sb[ni][3];
        const float aar = sarea[ni];
        for (int jj = tid; jj < V; jj += 256) {
            if (jj > i && srem[jj]) {
                const int nj = sidx[jj];
                const float ix1 = fmaxf(ax1, sb[nj][0]);
                const float iy1 = fmaxf(ay1, sb[nj][1]);
                const float ix2 = fminf(ax2, sb[nj][2]);
                const float iy2 = fminf(ay2, sb[nj][3]);
                const float iw = fmaxf(ix2 - ix1, 0.0f);
                const float ih = fmaxf(iy2 - iy1, 0.0f);
                const float inter = iw * ih;
                const float iou = inter / (aar + sarea[nj] - inter + 1e-9f);
                if (iou > 0.4f) srem[jj] = 0;
            }
        }
    }
    __syncthreads();

    // Write cls_dets + keep (scatter back to original index via sidx).
    for (int i = tid; i < BN; i += 256) {
        const int n    = sidx[i];
        const int kept = srem[i];
        const size_t obase = (size_t)(b * NFG + cc) * BN + n;
        keep_out[obase] = kept ? 1.0f : 0.0f;
        float* cd = cls_dets + obase * 5;
        if (kept) {
            cd[0] = sb[n][0]; cd[1] = sb[n][1];
            cd[2] = sb[n][2]; cd[3] = sb[n][3];
            cd[4] = skey[i];   // kept implies valid, key == score
        } else {
            cd[0] = 0.0f; cd[1] = 0.0f; cd[2] = 0.0f; cd[3] = 0.0f; cd[4] = 0.0f;
        }
    }
}

// -------------------- Kernel 2: kept_feats = any-class-keep ? feats : 0 -----
// One block per (b, n); 256 threads move 2048 floats as float4.
__global__ __launch_bounds__(256) void feat_kernel(
    const float* __restrict__ feats,     // [B,BN,FD]
    const float* __restrict__ keepf,     // [B,NFG,BN] (0/1 floats)
    float* __restrict__ out_feats)       // [B,BN,FD]
{
    const int bn = blockIdx.x;
    const int b  = bn >> 9;
    const int n  = bn & (BN - 1);

    __shared__ int s_any;
    if (threadIdx.x == 0) s_any = 0;
    __syncthreads();
    if (threadIdx.x < NFG) {
        if (keepf[((size_t)b * NFG + threadIdx.x) * BN + n] != 0.0f)
            s_any = 1;   // benign race: all writers store 1
    }
    __syncthreads();
    const float m = s_any ? 1.0f : 0.0f;

    const float4* src = (const float4*)(feats + (size_t)(b * BN + n) * FD);
    float4*       dst = (float4*)(out_feats + (size_t)(b * BN + n) * FD);
    for (int t = threadIdx.x; t < FD / 4; t += 256) {
        float4 v = src[t];
        dst[t] = make_float4(v.x * m, v.y * m, v.z * m, v.w * m);
    }
}

extern "C" void kernel_launch(void* const* d_in, const int* in_sizes, int n_in,
                              void* d_out, int out_size, void* d_ws, size_t ws_size,
                              hipStream_t stream) {
    const float* rois      = (const float*)d_in[0];  // [8,512,5]
    const float* bbox_pred = (const float*)d_in[1];  // [8,512,148]
    const float* scores    = (const float*)d_in[2];  // [8,512,37]
    const float* im_info   = (const float*)d_in[3];  // [8,3]
    const float* feats     = (const float*)d_in[4];  // [8,512,2048]

    float* out        = (float*)d_out;
    float* cls_dets   = out;                                     // 737280
    float* kept_feats = out + (size_t)BATCH * NFG * BN * 5;      // 8388608
    float* keep_out   = kept_feats + (size_t)BATCH * BN * FD;    // 147456

    nms_kernel<<<BATCH * NFG, 256, 0, stream>>>(rois, bbox_pred, scores, im_info,
                                                cls_dets, keep_out);
    feat_kernel<<<BATCH * BN, 256, 0, stream>>>(feats, keep_out, kept_feats);
}

// Round 2
// 112.077 us; speedup vs baseline: 1.2145x; 1.2145x over previous
//
#include <hip/hip_runtime.h>
#include <math.h>

#define BATCH 8
#define BN    512          // rois per frame
#define NC    37           // classes incl. background
#define NFG   36           // foreground classes
#define FD    2048         // feature dim

// Output layout (flat float32 in d_out, reference return order):
//   cls_dets  [B, NFG, BN, 5]  -> 737280 floats at offset 0
//   kept_feats[B, BN, FD]      -> 8388608 floats at offset 737280
//   keep      [B, NFG, BN]     -> 147456 floats (0/1) at offset 9125888

// -------------------- Kernel 1: decode + compact + sort + greedy NMS --------
// ONE WAVE (64 threads) per (batch, fg-class) problem. All "__syncthreads"
// are single-wave (compiler elides s_barrier; they order LDS accesses only).
__global__ __launch_bounds__(64) void nms_kernel(
    const float* __restrict__ rois,       // [B,BN,5] (bidx,x1,y1,x2,y2)
    const float* __restrict__ bbox_pred,  // [B,BN,4*NC]
    const float* __restrict__ scores,     // [B,BN,NC]
    const float* __restrict__ im_info,    // [B,3] (h,w,scale)
    float* __restrict__ cls_dets,         // [B,NFG,BN,5]
    float* __restrict__ keep_out,         // [B,NFG,BN]
    int*   __restrict__ anykeep)          // [B,BN] (pre-zeroed)
{
    const int bc   = blockIdx.x;
    const int b    = bc / NFG;
    const int cc   = bc % NFG;   // 0..35
    const int c    = cc + 1;     // class index 1..36
    const int lane = threadIdx.x;

    __shared__ float sb[BN][4];    // decoded clipped boxes, by ORIGINAL index (valid only)
    __shared__ float sarea[BN];    // areas, by original index (valid only)
    __shared__ float cscore[BN];   // compacted scores
    __shared__ int   cn[BN];       // compacted original indices
    __shared__ float kflag[BN];    // 0 = not kept; score (>0.1) = kept
    __shared__ unsigned char srem[BN];  // generic-path remaining flags

    const float xmax = im_info[b * 3 + 1] - 1.0f;
    const float ymax = im_info[b * 3 + 0] - 1.0f;
    const unsigned long long lmask_lt = (lane == 0) ? 0ull : ((1ull << lane) - 1ull);

    // ---- load scores (8 per lane), compact valid, decode boxes for valid ----
    float sc[8];
#pragma unroll
    for (int r = 0; r < 8; ++r) {
        const int n = r * 64 + lane;
        sc[r] = scores[(size_t)(b * BN + n) * NC + c];
        kflag[n] = 0.0f;
    }
    int base = 0;
#pragma unroll
    for (int r = 0; r < 8; ++r) {
        const int n = r * 64 + lane;
        const bool valid = sc[r] > 0.1f;
        const unsigned long long m = __ballot(valid);
        if (valid) {
            const int pos = base + __popcll(m & lmask_lt);
            cscore[pos] = sc[r];
            cn[pos] = n;
            // decode + clip this box
            const float* rr = rois + (size_t)(b * BN + n) * 5;
            const float x1r = rr[1], y1r = rr[2], x2r = rr[3], y2r = rr[4];
            const float w  = x2r - x1r;
            const float h  = y2r - y1r;
            const float cx = x1r + 0.5f * w;
            const float cy = y1r + 0.5f * h;
            const float* dp = bbox_pred + (size_t)(b * BN + n) * (4 * NC) + 4 * c;
            const float px = (dp[0] * 0.1f) * w + cx;
            const float py = (dp[1] * 0.1f) * h + cy;
            const float pw = expf(dp[2] * 0.2f) * w;
            const float ph = expf(dp[3] * 0.2f) * h;
            float bx1 = fminf(fmaxf(px - 0.5f * pw, 0.0f), xmax);
            float by1 = fminf(fmaxf(py - 0.5f * ph, 0.0f), ymax);
            float bx2 = fminf(fmaxf(px + 0.5f * pw, 0.0f), xmax);
            float by2 = fminf(fmaxf(py + 0.5f * ph, 0.0f), ymax);
            sb[n][0] = bx1; sb[n][1] = by1; sb[n][2] = bx2; sb[n][3] = by2;
            sarea[n] = (bx2 - bx1) * (by2 - by1);
        }
        base += __popcll(m);
    }
    const int V = base;   // wave-uniform
    __syncthreads();

    if (V <= 64) {
        // ---------------- fast path: register bitonic sort + ballot greedy ----
        float key; int id;
        if (lane < V) { key = cscore[lane]; id = cn[lane]; }
        else          { key = -INFINITY;    id = BN + lane; }
        // bitonic sort 64 lanes: (score desc, index asc)
#pragma unroll
        for (int k = 2; k <= 64; k <<= 1) {
#pragma unroll
            for (int j = k >> 1; j > 0; j >>= 1) {
                const float ok = __shfl_xor(key, j);
                const int   oi = __shfl_xor(id, j);
                const bool is_lower   = (lane & j) == 0;
                const bool dir_desc   = (lane & k) == 0;
                const bool mine_first = (key > ok) || (key == ok && id < oi);
                bool take = mine_first ^ is_lower;     // descending rule
                if (!dir_desc) take = !take;           // ascending region flips
                if (take) { key = ok; id = oi; }
            }
        }
        // fetch my sorted box
        float x1 = 0, y1 = 0, x2 = 0, y2 = 0, ar = 0;
        if (lane < V) { x1 = sb[id][0]; y1 = sb[id][1]; x2 = sb[id][2]; y2 = sb[id][3]; ar = sarea[id]; }
        unsigned long long rem = (V == 64) ? ~0ull : ((1ull << V) - 1ull);
        for (int i = 0; i < V; ++i) {
            if (!((rem >> i) & 1ull)) continue;        // wave-uniform
            const float ax1 = __shfl(x1, i);
            const float ay1 = __shfl(y1, i);
            const float ax2 = __shfl(x2, i);
            const float ay2 = __shfl(y2, i);
            const float aar = __shfl(ar, i);
            const float ix1 = fmaxf(ax1, x1);
            const float iy1 = fmaxf(ay1, y1);
            const float ix2 = fminf(ax2, x2);
            const float iy2 = fminf(ay2, y2);
            const float iw = fmaxf(ix2 - ix1, 0.0f);
            const float ih = fmaxf(iy2 - iy1, 0.0f);
            const float inter = iw * ih;
            const float iou = inter / (aar + ar - inter + 1e-9f);
            const unsigned long long sup = __ballot((iou > 0.4f) && (lane > i));
            rem &= ~sup;
        }
        if (lane < V && ((rem >> lane) & 1ull)) {
            kflag[id] = key;                  // kept: record score by original index
            anykeep[b * BN + id] = 1;         // benign race: all writers store 1
        }
    } else {
        // ---------------- generic path (V > 64): LDS bitonic + LDS greedy ----
        int P = 64; while (P < V) P <<= 1;
        for (int i = lane; i < P; i += 64) {
            if (i >= V) { cscore[i] = -INFINITY; cn[i] = BN + i; }
            srem[i] = (i < V) ? 1 : 0;
        }
        __syncthreads();
        for (int k = 2; k <= P; k <<= 1) {
            for (int j = k >> 1; j > 0; j >>= 1) {
                __syncthreads();
                for (int i = lane; i < P; i += 64) {
                    const int ixj = i ^ j;
                    if (ixj > i) {
                        const float ka = cscore[i], kb = cscore[ixj];
                        const int   ia = cn[i],     ib = cn[ixj];
                        const bool a_first = (ka > kb) || (ka == kb && ia < ib);
                        const bool up = ((i & k) == 0);
                        if (up ? !a_first : a_first) {
                            cscore[i] = kb; cscore[ixj] = ka;
                            cn[i] = ib;     cn[ixj] = ia;
                        }
                    }
                }
            }
        }
        __syncthreads();
        for (int i = 0; i < V; ++i) {
            __syncthreads();
            if (!srem[i]) continue;
            const int   ni  = cn[i];
            const float ax1 = sb[ni][0], ay1 = sb[ni][1];
            const float ax2 = sb[ni][2], ay2 = sb[ni][3];
            const float aar = sarea[ni];
            for (int jj = lane; jj < V; jj += 64) {
                if (jj > i && srem[jj]) {
                    const int nj = cn[jj];
                    const float ix1 = fmaxf(ax1, sb[nj][0]);
                    const float iy1 = fmaxf(ay1, sb[nj][1]);
                    const float ix2 = fminf(ax2, sb[nj][2]);
                    const float iy2 = fminf(ay2, sb[nj][3]);
                    const float iw = fmaxf(ix2 - ix1, 0.0f);
                    const float ih = fmaxf(iy2 - iy1, 0.0f);
                    const float inter = iw * ih;
                    const float iou = inter / (aar + sarea[nj] - inter + 1e-9f);
                    if (iou > 0.4f) srem[jj] = 0;
                }
            }
        }
        __syncthreads();
        for (int i = lane; i < V; i += 64) {
            if (srem[i]) {
                kflag[cn[i]] = cscore[i];
                anykeep[b * BN + cn[i]] = 1;
            }
        }
    }
    __syncthreads();

    // ---- unified output pass: every (n) written exactly once ----
    const size_t rowbase = (size_t)(b * NFG + cc) * BN;
#pragma unroll
    for (int r = 0; r < 8; ++r) {
        const int n = r * 64 + lane;
        const float s = kflag[n];
        const bool kept = s > 0.0f;
        keep_out[rowbase + n] = kept ? 1.0f : 0.0f;
        float* cd = cls_dets + (rowbase + n) * 5;
        cd[0] = kept ? sb[n][0] : 0.0f;
        cd[1] = kept ? sb[n][1] : 0.0f;
        cd[2] = kept ? sb[n][2] : 0.0f;
        cd[3] = kept ? sb[n][3] : 0.0f;
        cd[4] = kept ? s : 0.0f;
    }
}

// -------------------- Kernel 2: kept_feats = anykeep ? feats : 0 ------------
// One block per (b, n); skip the feature READ entirely for dropped rois.
__global__ __launch_bounds__(256) void feat_kernel(
    const float* __restrict__ feats,     // [B,BN,FD]
    const int*   __restrict__ anykeep,   // [B,BN]
    float* __restrict__ out_feats)       // [B,BN,FD]
{
    const int bn = blockIdx.x;
    const int flag = anykeep[bn];        // uniform load
    const float4* src = (const float4*)(feats + (size_t)bn * FD);
    float4*       dst = (float4*)(out_feats + (size_t)bn * FD);
    if (flag) {
#pragma unroll
        for (int t = threadIdx.x; t < FD / 4; t += 256) dst[t] = src[t];
    } else {
        const float4 z = make_float4(0.f, 0.f, 0.f, 0.f);
#pragma unroll
        for (int t = threadIdx.x; t < FD / 4; t += 256) dst[t] = z;
    }
}

extern "C" void kernel_launch(void* const* d_in, const int* in_sizes, int n_in,
                              void* d_out, int out_size, void* d_ws, size_t ws_size,
                              hipStream_t stream) {
    const float* rois      = (const float*)d_in[0];  // [8,512,5]
    const float* bbox_pred = (const float*)d_in[1];  // [8,512,148]
    const float* scores    = (const float*)d_in[2];  // [8,512,37]
    const float* im_info   = (const float*)d_in[3];  // [8,3]
    const float* feats     = (const float*)d_in[4];  // [8,512,2048]

    float* out        = (float*)d_out;
    float* cls_dets   = out;                                     // 737280
    float* kept_feats = out + (size_t)BATCH * NFG * BN * 5;      // 8388608
    float* keep_out   = kept_feats + (size_t)BATCH * BN * FD;    // 147456

    int* anykeep = (int*)d_ws;                                   // [B*BN]
    hipMemsetAsync(anykeep, 0, (size_t)BATCH * BN * sizeof(int), stream);

    nms_kernel<<<BATCH * NFG, 64, 0, stream>>>(rois, bbox_pred, scores, im_info,
                                               cls_dets, keep_out, anykeep);
    feat_kernel<<<BATCH * BN, 256, 0, stream>>>(feats, anykeep, kept_feats);
}

// Round 3
// 109.209 us; speedup vs baseline: 1.2464x; 1.0263x over previous
//
#include <hip/hip_runtime.h>
#include <math.h>

#define BATCH 8
#define BN    512          // rois per frame
#define NC    37           // classes incl. background
#define NFG   36           // foreground classes
#define FD    2048         // feature dim

// Output layout (flat float32 in d_out, reference return order):
//   cls_dets  [B, NFG, BN, 5]  -> 737280 floats at offset 0
//   kept_feats[B, BN, FD]      -> 8388608 floats at offset 737280
//   keep      [B, NFG, BN]     -> 147456 floats (0/1) at offset 9125888

// -------------------- Kernel 1: decode + compact + sort + greedy NMS --------
// ONE WAVE (64 threads) per (batch, fg-class). 288 waves total -> pure
// latency regime: prefetch ALL inputs up front (independent loads), decode
// unconditionally, then compact/sort/suppress in registers.
__global__ __launch_bounds__(64) void nms_kernel(
    const float* __restrict__ rois,       // [B,BN,5] (bidx,x1,y1,x2,y2)
    const float* __restrict__ bbox_pred,  // [B,BN,4*NC]
    const float* __restrict__ scores,     // [B,BN,NC]
    const float* __restrict__ im_info,    // [B,3] (h,w,scale)
    float* __restrict__ cls_dets,         // [B,NFG,BN,5]
    float* __restrict__ keep_out)         // [B,NFG,BN]
{
    const int bc   = blockIdx.x;
    const int b    = bc / NFG;
    const int cc   = bc % NFG;   // 0..35
    const int c    = cc + 1;     // class index 1..36
    const int lane = threadIdx.x;

    __shared__ float sb[BN][4];    // decoded clipped boxes, by original index
    __shared__ float sarea[BN];    // areas, by original index
    __shared__ float cscore[BN];   // compacted scores
    __shared__ int   cn[BN];       // compacted original indices
    __shared__ float kflag[BN];    // 0 = not kept; score (>0.1) = kept
    __shared__ unsigned char srem[BN];  // generic-path remaining flags

    const float xmax = im_info[b * 3 + 1] - 1.0f;
    const float ymax = im_info[b * 3 + 0] - 1.0f;
    const unsigned long long lmask_lt = (lane == 0) ? 0ull : ((1ull << lane) - 1ull);

    // ---- prefetch everything (independent loads, one latency round) --------
    float  sc[8];
    float4 bp[8];                 // bbox_pred[..., 4c:4c+4] (16B-aligned: 592|16, 16c|16)
    float  rx1[8], ry1[8], rx2[8], ry2[8];
#pragma unroll
    for (int r = 0; r < 8; ++r) {
        const int n = r * 64 + lane;
        sc[r] = scores[(size_t)(b * BN + n) * NC + c];
        bp[r] = *(const float4*)(bbox_pred + (size_t)(b * BN + n) * (4 * NC) + 4 * c);
        const float* rr = rois + (size_t)(b * BN + n) * 5;
        rx1[r] = rr[1]; ry1[r] = rr[2]; rx2[r] = rr[3]; ry2[r] = rr[4];
        kflag[n] = 0.0f;
    }

    // ---- decode + clip ALL boxes (VALU is free at this occupancy) ----------
#pragma unroll
    for (int r = 0; r < 8; ++r) {
        const int n = r * 64 + lane;
        const float w  = rx2[r] - rx1[r];
        const float h  = ry2[r] - ry1[r];
        const float cx = rx1[r] + 0.5f * w;
        const float cy = ry1[r] + 0.5f * h;
        const float px = (bp[r].x * 0.1f) * w + cx;
        const float py = (bp[r].y * 0.1f) * h + cy;
        const float pw = expf(bp[r].z * 0.2f) * w;
        const float ph = expf(bp[r].w * 0.2f) * h;
        const float bx1 = fminf(fmaxf(px - 0.5f * pw, 0.0f), xmax);
        const float by1 = fminf(fmaxf(py - 0.5f * ph, 0.0f), ymax);
        const float bx2 = fminf(fmaxf(px + 0.5f * pw, 0.0f), xmax);
        const float by2 = fminf(fmaxf(py + 0.5f * ph, 0.0f), ymax);
        sb[n][0] = bx1; sb[n][1] = by1; sb[n][2] = bx2; sb[n][3] = by2;
        sarea[n] = (bx2 - bx1) * (by2 - by1);
    }

    // ---- compact valid (score > 0.1) into sorted-input arrays --------------
    int base = 0;
#pragma unroll
    for (int r = 0; r < 8; ++r) {
        const int n = r * 64 + lane;
        const bool valid = sc[r] > 0.1f;
        const unsigned long long m = __ballot(valid);
        if (valid) {
            const int pos = base + __popcll(m & lmask_lt);
            cscore[pos] = sc[r];
            cn[pos] = n;
        }
        base += __popcll(m);
    }
    const int V = base;   // wave-uniform
    __syncthreads();

    if (V <= 64) {
        // ---------------- fast path: register bitonic sort + ballot greedy ----
        float key; int id;
        if (lane < V) { key = cscore[lane]; id = cn[lane]; }
        else          { key = -INFINITY;    id = BN + lane; }
        // bitonic sort 64 lanes: (score desc, index asc)
#pragma unroll
        for (int k = 2; k <= 64; k <<= 1) {
#pragma unroll
            for (int j = k >> 1; j > 0; j >>= 1) {
                const float ok = __shfl_xor(key, j);
                const int   oi = __shfl_xor(id, j);
                const bool is_lower   = (lane & j) == 0;
                const bool dir_desc   = (lane & k) == 0;
                const bool mine_first = (key > ok) || (key == ok && id < oi);
                bool take = mine_first ^ is_lower;     // descending rule
                if (!dir_desc) take = !take;           // ascending region flips
                if (take) { key = ok; id = oi; }
            }
        }
        // fetch my sorted box
        float x1 = 0, y1 = 0, x2 = 0, y2 = 0, ar = 0;
        if (lane < V) { x1 = sb[id][0]; y1 = sb[id][1]; x2 = sb[id][2]; y2 = sb[id][3]; ar = sarea[id]; }
        unsigned long long rem = (V == 64) ? ~0ull : ((1ull << V) - 1ull);
        for (int i = 0; i < V; ++i) {
            if (!((rem >> i) & 1ull)) continue;        // wave-uniform
            const float ax1 = __shfl(x1, i);
            const float ay1 = __shfl(y1, i);
            const float ax2 = __shfl(x2, i);
            const float ay2 = __shfl(y2, i);
            const float aar = __shfl(ar, i);
            const float ix1 = fmaxf(ax1, x1);
            const float iy1 = fmaxf(ay1, y1);
            const float ix2 = fminf(ax2, x2);
            const float iy2 = fminf(ay2, y2);
            const float iw = fmaxf(ix2 - ix1, 0.0f);
            const float ih = fmaxf(iy2 - iy1, 0.0f);
            const float inter = iw * ih;
            const float iou = inter / (aar + ar - inter + 1e-9f);
            const unsigned long long sup = __ballot((iou > 0.4f) && (lane > i));
            rem &= ~sup;
        }
        if (lane < V && ((rem >> lane) & 1ull)) {
            kflag[id] = key;                  // kept: record score by original index
        }
    } else {
        // ---------------- generic path (V > 64): LDS bitonic + LDS greedy ----
        int P = 64; while (P < V) P <<= 1;
        for (int i = lane; i < P; i += 64) {
            if (i >= V) { cscore[i] = -INFINITY; cn[i] = BN + i; }
            srem[i] = (i < V) ? 1 : 0;
        }
        __syncthreads();
        for (int k = 2; k <= P; k <<= 1) {
            for (int j = k >> 1; j > 0; j >>= 1) {
                __syncthreads();
                for (int i = lane; i < P; i += 64) {
                    const int ixj = i ^ j;
                    if (ixj > i) {
                        const float ka = cscore[i], kb = cscore[ixj];
                        const int   ia = cn[i],     ib = cn[ixj];
                        const bool a_first = (ka > kb) || (ka == kb && ia < ib);
                        const bool up = ((i & k) == 0);
                        if (up ? !a_first : a_first) {
                            cscore[i] = kb; cscore[ixj] = ka;
                            cn[i] = ib;     cn[ixj] = ia;
                        }
                    }
                }
            }
        }
        __syncthreads();
        for (int i = 0; i < V; ++i) {
            __syncthreads();
            if (!srem[i]) continue;
            const int   ni  = cn[i];
            const float ax1 = sb[ni][0], ay1 = sb[ni][1];
            const float ax2 = sb[ni][2], ay2 = sb[ni][3];
            const float aar = sarea[ni];
            for (int jj = lane; jj < V; jj += 64) {
                if (jj > i && srem[jj]) {
                    const int nj = cn[jj];
                    const float ix1 = fmaxf(ax1, sb[nj][0]);
                    const float iy1 = fmaxf(ay1, sb[nj][1]);
                    const float ix2 = fminf(ax2, sb[nj][2]);
                    const float iy2 = fminf(ay2, sb[nj][3]);
                    const float iw = fmaxf(ix2 - ix1, 0.0f);
                    const float ih = fmaxf(iy2 - iy1, 0.0f);
                    const float inter = iw * ih;
                    const float iou = inter / (aar + sarea[nj] - inter + 1e-9f);
                    if (iou > 0.4f) srem[jj] = 0;
                }
            }
        }
        __syncthreads();
        for (int i = lane; i < V; i += 64) {
            if (srem[i]) kflag[cn[i]] = cscore[i];
        }
    }
    __syncthreads();

    // ---- unified output pass: every (n) written exactly once ----
    const size_t rowbase = (size_t)(b * NFG + cc) * BN;
#pragma unroll
    for (int r = 0; r < 8; ++r) {
        const int n = r * 64 + lane;
        const float s = kflag[n];
        const bool kept = s > 0.0f;
        keep_out[rowbase + n] = kept ? 1.0f : 0.0f;
        float* cd = cls_dets + (rowbase + n) * 5;
        cd[0] = kept ? sb[n][0] : 0.0f;
        cd[1] = kept ? sb[n][1] : 0.0f;
        cd[2] = kept ? sb[n][2] : 0.0f;
        cd[3] = kept ? sb[n][3] : 0.0f;
        cd[4] = kept ? s : 0.0f;
    }
}

// -------------------- Kernel 2: kept_feats = any(keep[:,n]) ? feats : 0 -----
// One block per (b, n); any-keep derived from keep_out (L2-resident, 147 KB)
// so no scratch array / no memset dispatch. Skip the feature READ for
// dropped rois.
__global__ __launch_bounds__(256) void feat_kernel(
    const float* __restrict__ feats,     // [B,BN,FD]
    const float* __restrict__ keepf,     // [B,NFG,BN] (0/1 floats)
    float* __restrict__ out_feats)       // [B,BN,FD]
{
    const int bn = blockIdx.x;
    const int b  = bn >> 9;
    const int n  = bn & (BN - 1);

    __shared__ int s_any;
    if (threadIdx.x == 0) s_any = 0;
    __syncthreads();
    if (threadIdx.x < NFG) {
        if (keepf[((size_t)b * NFG + threadIdx.x) * BN + n] != 0.0f)
            s_any = 1;   // benign race: all writers store 1
    }
    __syncthreads();

    const float4* src = (const float4*)(feats + (size_t)bn * FD);
    float4*       dst = (float4*)(out_feats + (size_t)bn * FD);
    if (s_any) {
#pragma unroll
        for (int t = threadIdx.x; t < FD / 4; t += 256) dst[t] = src[t];
    } else {
        const float4 z = make_float4(0.f, 0.f, 0.f, 0.f);
#pragma unroll
        for (int t = threadIdx.x; t < FD / 4; t += 256) dst[t] = z;
    }
}

extern "C" void kernel_launch(void* const* d_in, const int* in_sizes, int n_in,
                              void* d_out, int out_size, void* d_ws, size_t ws_size,
                              hipStream_t stream) {
    const float* rois      = (const float*)d_in[0];  // [8,512,5]
    const float* bbox_pred = (const float*)d_in[1];  // [8,512,148]
    const float* scores    = (const float*)d_in[2];  // [8,512,37]
    const float* im_info   = (const float*)d_in[3];  // [8,3]
    const float* feats     = (const float*)d_in[4];  // [8,512,2048]

    float* out        = (float*)d_out;
    float* cls_dets   = out;                                     // 737280
    float* kept_feats = out + (size_t)BATCH * NFG * BN * 5;      // 8388608
    float* keep_out   = kept_feats + (size_t)BATCH * BN * FD;    // 147456

    nms_kernel<<<BATCH * NFG, 64, 0, stream>>>(rois, bbox_pred, scores, im_info,
                                               cls_dets, keep_out);
    feat_kernel<<<BATCH * BN, 256, 0, stream>>>(feats, keep_out, kept_feats);
}

// Round 4
// 108.961 us; speedup vs baseline: 1.2493x; 1.0023x over previous
//
#include <hip/hip_runtime.h>
#include <math.h>

#define BATCH 8
#define BN    512          // rois per frame
#define NC    37           // classes incl. background
#define NFG   36           // foreground classes
#define FD    2048         // feature dim
#define NW    2            // waves (= independent problems) per nms block

// Output layout (flat float32 in d_out, reference return order):
//   cls_dets  [B, NFG, BN, 5]  -> 737280 floats at offset 0
//   kept_feats[B, BN, FD]      -> 8388608 floats at offset 737280
//   keep      [B, NFG, BN]     -> 147456 floats (0/1) at offset 9125888
// d_ws: keep_t [B, BN, NFG] bytes (147456 B) — transposed keep for feat_kernel.

// -------------------- Kernel 1: decode + compact + sort + greedy NMS --------
// 144 blocks x 128 threads; each WAVE owns one (batch, fg-class) problem.
// One block per CU (no tail round). No __syncthreads — each wave uses its own
// LDS slab; in-wave LDS RAW ordering comes from compiler lgkmcnt waits, with
// wave_barrier() pinning instruction order at phase boundaries.
__global__ __launch_bounds__(128) void nms_kernel(
    const float* __restrict__ rois,       // [B,BN,5] (bidx,x1,y1,x2,y2)
    const float* __restrict__ bbox_pred,  // [B,BN,4*NC]
    const float* __restrict__ scores,     // [B,BN,NC]
    const float* __restrict__ im_info,    // [B,3] (h,w,scale)
    float* __restrict__ cls_dets,         // [B,NFG,BN,5]
    float* __restrict__ keep_out,         // [B,NFG,BN]
    unsigned char* __restrict__ keep_t)   // [B,BN,NFG] bytes
{
    const int wid  = threadIdx.x >> 6;
    const int lane = threadIdx.x & 63;
    const int bc   = blockIdx.x * NW + wid;   // 0..287
    const int b    = bc / NFG;
    const int cc   = bc % NFG;   // 0..35
    const int c    = cc + 1;     // class index 1..36

    __shared__ float sb[NW][BN][4];    // decoded clipped boxes, original index
    __shared__ float sarea[NW][BN];    // areas, original index
    __shared__ float cscore[NW][BN];   // compacted scores
    __shared__ int   cn[NW][BN];       // compacted original indices
    __shared__ float kflag[NW][BN];    // 0 = not kept; score = kept
    __shared__ unsigned char srem[NW][BN];  // generic-path remaining flags

    const float xmax = im_info[b * 3 + 1] - 1.0f;
    const float ymax = im_info[b * 3 + 0] - 1.0f;
    const unsigned long long lmask_lt = (lane == 0) ? 0ull : ((1ull << lane) - 1ull);

    // ---- prefetch everything (independent loads, one latency round) --------
    float  sc[8];
    float4 bp[8];                 // bbox_pred[..., 4c:4c+4] (16B-aligned)
    float  rx1[8], ry1[8], rx2[8], ry2[8];
#pragma unroll
    for (int r = 0; r < 8; ++r) {
        const int n = r * 64 + lane;
        sc[r] = scores[(size_t)(b * BN + n) * NC + c];
        bp[r] = *(const float4*)(bbox_pred + (size_t)(b * BN + n) * (4 * NC) + 4 * c);
        const float* rr = rois + (size_t)(b * BN + n) * 5;
        rx1[r] = rr[1]; ry1[r] = rr[2]; rx2[r] = rr[3]; ry2[r] = rr[4];
        kflag[wid][n] = 0.0f;
    }

    // ---- decode + clip ALL boxes (VALU is free at this occupancy) ----------
#pragma unroll
    for (int r = 0; r < 8; ++r) {
        const int n = r * 64 + lane;
        const float w  = rx2[r] - rx1[r];
        const float h  = ry2[r] - ry1[r];
        const float cx = rx1[r] + 0.5f * w;
        const float cy = ry1[r] + 0.5f * h;
        const float px = (bp[r].x * 0.1f) * w + cx;
        const float py = (bp[r].y * 0.1f) * h + cy;
        const float pw = expf(bp[r].z * 0.2f) * w;
        const float ph = expf(bp[r].w * 0.2f) * h;
        const float bx1 = fminf(fmaxf(px - 0.5f * pw, 0.0f), xmax);
        const float by1 = fminf(fmaxf(py - 0.5f * ph, 0.0f), ymax);
        const float bx2 = fminf(fmaxf(px + 0.5f * pw, 0.0f), xmax);
        const float by2 = fminf(fmaxf(py + 0.5f * ph, 0.0f), ymax);
        sb[wid][n][0] = bx1; sb[wid][n][1] = by1;
        sb[wid][n][2] = bx2; sb[wid][n][3] = by2;
        sarea[wid][n] = (bx2 - bx1) * (by2 - by1);
    }

    // ---- compact valid (score > 0.1) ---------------------------------------
    int base = 0;
#pragma unroll
    for (int r = 0; r < 8; ++r) {
        const int n = r * 64 + lane;
        const bool valid = sc[r] > 0.1f;
        const unsigned long long m = __ballot(valid);
        if (valid) {
            const int pos = base + __popcll(m & lmask_lt);
            cscore[wid][pos] = sc[r];
            cn[wid][pos] = n;
        }
        base += __popcll(m);
    }
    const int V = base;   // wave-uniform
    __builtin_amdgcn_wave_barrier();

    if (V <= 64) {
        // -------- fast path: register bitonic sort + masked greedy ----------
        float key; int id;
        if (lane < V) { key = cscore[wid][lane]; id = cn[wid][lane]; }
        else          { key = -INFINITY;         id = BN + lane; }
        // bitonic sort 64 lanes: (score desc, index asc)
#pragma unroll
        for (int k = 2; k <= 64; k <<= 1) {
#pragma unroll
            for (int j = k >> 1; j > 0; j >>= 1) {
                const float ok = __shfl_xor(key, j);
                const int   oi = __shfl_xor(id, j);
                const bool is_lower   = (lane & j) == 0;
                const bool dir_desc   = (lane & k) == 0;
                const bool mine_first = (key > ok) || (key == ok && id < oi);
                bool take = mine_first ^ is_lower;
                if (!dir_desc) take = !take;
                if (take) { key = ok; id = oi; }
            }
        }
        // fetch my sorted box
        float x1 = 0, y1 = 0, x2 = 0, y2 = 0, ar = 0;
        if (lane < V) {
            x1 = sb[wid][id][0]; y1 = sb[wid][id][1];
            x2 = sb[wid][id][2]; y2 = sb[wid][id][3];
            ar = sarea[wid][id];
        }
        // pipelined pass: column mask = which earlier boxes would suppress me
        unsigned long long colmask = 0;
        for (int i = 0; i < V; ++i) {
            const float ax1 = __shfl(x1, i);
            const float ay1 = __shfl(y1, i);
            const float ax2 = __shfl(x2, i);
            const float ay2 = __shfl(y2, i);
            const float aar = __shfl(ar, i);
            const float ix1 = fmaxf(ax1, x1);
            const float iy1 = fmaxf(ay1, y1);
            const float ix2 = fminf(ax2, x2);
            const float iy2 = fminf(ay2, y2);
            const float iw = fmaxf(ix2 - ix1, 0.0f);
            const float ih = fmaxf(iy2 - iy1, 0.0f);
            const float inter = iw * ih;
            const float iou = inter / (aar + ar - inter + 1e-9f);
            if ((iou > 0.4f) && (i < lane)) colmask |= (1ull << i);
        }
        // serial resolve: one ballot per surviving box
        unsigned long long rem = (V == 64) ? ~0ull : ((1ull << V) - 1ull);
        for (int i = 0; i < V; ++i) {
            if (!((rem >> i) & 1ull)) continue;        // wave-uniform
            rem &= ~__ballot((colmask >> i) & 1ull);
        }
        if (lane < V && ((rem >> lane) & 1ull)) {
            kflag[wid][id] = key;             // kept: record score by original index
        }
    } else {
        // -------- generic path (V > 64): LDS bitonic + LDS greedy -----------
        int P = 64; while (P < V) P <<= 1;
        for (int i = lane; i < P; i += 64) {
            if (i >= V) { cscore[wid][i] = -INFINITY; cn[wid][i] = BN + i; }
            srem[wid][i] = (i < V) ? 1 : 0;
        }
        __builtin_amdgcn_wave_barrier();
        for (int k = 2; k <= P; k <<= 1) {
            for (int j = k >> 1; j > 0; j >>= 1) {
                __builtin_amdgcn_wave_barrier();
                for (int i = lane; i < P; i += 64) {
                    const int ixj = i ^ j;
                    if (ixj > i) {
                        const float ka = cscore[wid][i], kb = cscore[wid][ixj];
                        const int   ia = cn[wid][i],     ib = cn[wid][ixj];
                        const bool a_first = (ka > kb) || (ka == kb && ia < ib);
                        const bool up = ((i & k) == 0);
                        if (up ? !a_first : a_first) {
                            cscore[wid][i] = kb; cscore[wid][ixj] = ka;
                            cn[wid][i] = ib;     cn[wid][ixj] = ia;
                        }
                    }
                }
            }
        }
        __builtin_amdgcn_wave_barrier();
        for (int i = 0; i < V; ++i) {
            __builtin_amdgcn_wave_barrier();
            if (!srem[wid][i]) continue;
            const int   ni  = cn[wid][i];
            const float ax1 = sb[wid][ni][0], ay1 = sb[wid][ni][1];
            const float ax2 = sb[wid][ni][2], ay2 = sb[wid][ni][3];
            const float aar = sarea[wid][ni];
            for (int jj = lane; jj < V; jj += 64) {
                if (jj > i && srem[wid][jj]) {
                    const int nj = cn[wid][jj];
                    const float ix1 = fmaxf(ax1, sb[wid][nj][0]);
                    const float iy1 = fmaxf(ay1, sb[wid][nj][1]);
                    const float ix2 = fminf(ax2, sb[wid][nj][2]);
                    const float iy2 = fminf(ay2, sb[wid][nj][3]);
                    const float iw = fmaxf(ix2 - ix1, 0.0f);
                    const float ih = fmaxf(iy2 - iy1, 0.0f);
                    const float inter = iw * ih;
                    const float iou = inter / (aar + sarea[wid][nj] - inter + 1e-9f);
                    if (iou > 0.4f) srem[wid][jj] = 0;
                }
            }
        }
        __builtin_amdgcn_wave_barrier();
        for (int i = lane; i < V; i += 64) {
            if (srem[wid][i]) kflag[wid][cn[wid][i]] = cscore[wid][i];
        }
    }
    __builtin_amdgcn_wave_barrier();

    // ---- unified output pass: every (n) written exactly once ----
    const size_t rowbase = (size_t)(b * NFG + cc) * BN;
#pragma unroll
    for (int r = 0; r < 8; ++r) {
        const int n = r * 64 + lane;
        const float s = kflag[wid][n];
        const bool kept = s > 0.0f;
        keep_out[rowbase + n] = kept ? 1.0f : 0.0f;
        keep_t[(size_t)(b * BN + n) * NFG + cc] = kept ? 1 : 0;
        float* cd = cls_dets + (rowbase + n) * 5;
        cd[0] = kept ? sb[wid][n][0] : 0.0f;
        cd[1] = kept ? sb[wid][n][1] : 0.0f;
        cd[2] = kept ? sb[wid][n][2] : 0.0f;
        cd[3] = kept ? sb[wid][n][3] : 0.0f;
        cd[4] = kept ? s : 0.0f;
    }
}

// -------------------- Kernel 2: kept_feats = any(keep_t[bn,:]) ? feats : 0 --
// One block per (b, n); any-keep = 9 contiguous dword loads (36 bytes).
__global__ __launch_bounds__(256) void feat_kernel(
    const float* __restrict__ feats,            // [B,BN,FD]
    const unsigned char* __restrict__ keep_t,   // [B,BN,NFG] bytes
    float* __restrict__ out_feats)              // [B,BN,FD]
{
    const int bn = blockIdx.x;

    __shared__ int s_any;
    if (threadIdx.x == 0) s_any = 0;
    __syncthreads();
    if (threadIdx.x < 9) {
        const unsigned int w = *(const unsigned int*)(keep_t + (size_t)bn * NFG
                                                      + 4 * threadIdx.x);
        if (w != 0u) s_any = 1;   // benign race: all writers store 1
    }
    __syncthreads();

    const float4* src = (const float4*)(feats + (size_t)bn * FD);
    float4*       dst = (float4*)(out_feats + (size_t)bn * FD);
    if (s_any) {
#pragma unroll
        for (int t = threadIdx.x; t < FD / 4; t += 256) dst[t] = src[t];
    } else {
        const float4 z = make_float4(0.f, 0.f, 0.f, 0.f);
#pragma unroll
        for (int t = threadIdx.x; t < FD / 4; t += 256) dst[t] = z;
    }
}

extern "C" void kernel_launch(void* const* d_in, const int* in_sizes, int n_in,
                              void* d_out, int out_size, void* d_ws, size_t ws_size,
                              hipStream_t stream) {
    const float* rois      = (const float*)d_in[0];  // [8,512,5]
    const float* bbox_pred = (const float*)d_in[1];  // [8,512,148]
    const float* scores    = (const float*)d_in[2];  // [8,512,37]
    const float* im_info   = (const float*)d_in[3];  // [8,3]
    const float* feats     = (const float*)d_in[4];  // [8,512,2048]

    float* out        = (float*)d_out;
    float* cls_dets   = out;                                     // 737280
    float* kept_feats = out + (size_t)BATCH * NFG * BN * 5;      // 8388608
    float* keep_out   = kept_feats + (size_t)BATCH * BN * FD;    // 147456

    unsigned char* keep_t = (unsigned char*)d_ws;  // [B,BN,NFG] bytes, fully rewritten

    nms_kernel<<<(BATCH * NFG) / NW, 64 * NW, 0, stream>>>(
        rois, bbox_pred, scores, im_info, cls_dets, keep_out, keep_t);
    feat_kernel<<<BATCH * BN, 256, 0, stream>>>(feats, keep_t, kept_feats);
}